// Round 2
// baseline (57.316 us; speedup 1.0000x reference)
//
#include <hip/hip_runtime.h>

#define NROWS  50000
#define NF     32
#define NTREES 300
#define NINT   63
#define NLEAF  64
#define LRATE  0.1f
#define RPB    256     // rows per block == threads per block
#define TPG    12      // trees per group (multiple of 6 for ILP-6, and of 3 classes)
#define TG     25      // tree groups (grid.y); TPG*TG == NTREES

__global__ void gb_init_out(const float* __restrict__ initp,
                            float* __restrict__ out, int n) {
    int i = blockIdx.x * blockDim.x + threadIdx.x;
    if (i < n) out[i] = initp[i % 3];
}

__global__ __launch_bounds__(RPB, 4) void gb_forest(
    const float* __restrict__ x,      // [NROWS][NF]
    const int*   __restrict__ feat,   // [NTREES][NINT]
    const float* __restrict__ thr,    // [NTREES][NINT]
    const float* __restrict__ leaves, // [NTREES][NLEAF]
    float*       __restrict__ out)    // [NROWS][3]
{
    // LDS: 32768 + 6144 = 38912 B -> 4 blocks/CU (16 waves/CU)
    __shared__ float xs[NF][RPB];     // transposed: read bank = tid%32, conflict-free
    __shared__ int2  nodes[TPG][64];  // packed {feature, threshold_bits}

    const int tid  = threadIdx.x;
    const int r0   = blockIdx.x * RPB;
    const int m0   = blockIdx.y * TPG;
    const int grow = r0 + tid;

    // --- stage x: each thread loads ITS OWN row (8x float4, L1-merged),
    //     writes transposed -> write bank = tid%32 -> conflict-free ---
    {
        const float4* xr = (const float4*)x + (size_t)(grow < NROWS ? grow : NROWS - 1) * (NF / 4);
        float4 v[8];
        #pragma unroll
        for (int k = 0; k < 8; ++k) v[k] = xr[k];
        #pragma unroll
        for (int k = 0; k < 8; ++k) {
            xs[k * 4 + 0][tid] = v[k].x;
            xs[k * 4 + 1][tid] = v[k].y;
            xs[k * 4 + 2][tid] = v[k].z;
            xs[k * 4 + 3][tid] = v[k].w;
        }
    }
    // --- stage this group's tree nodes packed into LDS (756 int2) ---
    for (int i = tid; i < TPG * NINT; i += RPB) {
        int tl = i / NINT;
        int nd = i - tl * NINT;
        int gi = (m0 + tl) * NINT + nd;
        nodes[tl][nd] = make_int2(feat[gi], __float_as_int(thr[gi]));
    }
    __syncthreads();

    // --- walk 6 trees concurrently (classes 0,1,2,0,1,2), 6 levels each ---
    float acc0 = 0.f, acc1 = 0.f, acc2 = 0.f;
    #pragma unroll
    for (int it = 0; it < TPG; it += 6) {
        int i0 = 0, i1 = 0, i2 = 0, i3 = 0, i4 = 0, i5 = 0;
        #pragma unroll
        for (int d = 0; d < 6; ++d) {
            int2 A = nodes[it + 0][i0];
            int2 B = nodes[it + 1][i1];
            int2 C = nodes[it + 2][i2];
            int2 D = nodes[it + 3][i3];
            int2 E = nodes[it + 4][i4];
            int2 F = nodes[it + 5][i5];
            // sklearn: left (+1) iff x <= t, right (+2) otherwise
            i0 = 2 * i0 + 1 + (int)(xs[A.x][tid] > __int_as_float(A.y));
            i1 = 2 * i1 + 1 + (int)(xs[B.x][tid] > __int_as_float(B.y));
            i2 = 2 * i2 + 1 + (int)(xs[C.x][tid] > __int_as_float(C.y));
            i3 = 2 * i3 + 1 + (int)(xs[D.x][tid] > __int_as_float(D.y));
            i4 = 2 * i4 + 1 + (int)(xs[E.x][tid] > __int_as_float(E.y));
            i5 = 2 * i5 + 1 + (int)(xs[F.x][tid] > __int_as_float(F.y));
        }
        acc0 += leaves[(m0 + it + 0) * NLEAF + (i0 - NINT)]
              + leaves[(m0 + it + 3) * NLEAF + (i3 - NINT)];
        acc1 += leaves[(m0 + it + 1) * NLEAF + (i1 - NINT)]
              + leaves[(m0 + it + 4) * NLEAF + (i4 - NINT)];
        acc2 += leaves[(m0 + it + 2) * NLEAF + (i2 - NINT)]
              + leaves[(m0 + it + 5) * NLEAF + (i5 - NINT)];
    }

    if (grow < NROWS) {
        atomicAdd(&out[grow * 3 + 0], LRATE * acc0);
        atomicAdd(&out[grow * 3 + 1], LRATE * acc1);
        atomicAdd(&out[grow * 3 + 2], LRATE * acc2);
    }
}

extern "C" void kernel_launch(void* const* d_in, const int* in_sizes, int n_in,
                              void* d_out, int out_size, void* d_ws, size_t ws_size,
                              hipStream_t stream) {
    const float* x      = (const float*)d_in[0];
    const int*   feat   = (const int*)d_in[1];
    const float* thr    = (const float*)d_in[2];
    const float* leaves = (const float*)d_in[3];
    const float* initp  = (const float*)d_in[4];
    float* out = (float*)d_out;

    gb_init_out<<<(out_size + 255) / 256, 256, 0, stream>>>(initp, out, out_size);

    dim3 grid((NROWS + RPB - 1) / RPB, TG);
    gb_forest<<<grid, RPB, 0, stream>>>(x, feat, thr, leaves, out);
}